// Round 13
// baseline (408.418 us; speedup 1.0000x reference)
//
#include <hip/hip_runtime.h>

typedef _Float16 f16;
typedef _Float16 half8 __attribute__((ext_vector_type(8)));
typedef _Float16 half4 __attribute__((ext_vector_type(4)));
typedef float floatx4 __attribute__((ext_vector_type(4)));

#define MFMA16(a, b, c) __builtin_amdgcn_mfma_f32_16x16x32_f16(a, b, c, 0, 0, 0)

// counted-vmcnt phase gate: wait until only the NEXT tile's 4 staging loads
// remain in flight (FIFO: current tile's 4 are older -> retired first),
// fence the scheduler, then raw barrier (no implicit drain).
#define PHASE_WAIT_4()  do { asm volatile("s_waitcnt vmcnt(4)" ::: "memory"); \
    __builtin_amdgcn_sched_barrier(0); __builtin_amdgcn_s_barrier(); } while (0)
#define PHASE_WAIT_0()  do { asm volatile("s_waitcnt vmcnt(0)" ::: "memory"); \
    __builtin_amdgcn_sched_barrier(0); __builtin_amdgcn_s_barrier(); } while (0)

// async global->LDS, 16B per lane; LDS side = wave-uniform base + lane*16
__device__ __forceinline__ void gload16(const void* g, void* l) {
    __builtin_amdgcn_global_load_lds((const __attribute__((address_space(1))) void*)g,
                                     (__attribute__((address_space(3))) void*)l, 16, 0, 0);
}

// ---------------------------------------------------------------------------
// v8 theory: unified VGPR+AGPR (~100 arch + 64 acc) put every GEMM wave in
// the 129-256 reg bracket -> 2 waves/SIMD -> 8 waves/CU (25% cap; measured
// 19% in r3/r4/r10/r12 regardless of LDS). Fix: 8 waves per 128x128 tile
// (512-thread blocks, per-wave 64x32 -> acc[4][2]=32 AGPR) + launch_bounds
// (512,4) to force <=128 total regs -> 4 waves/SIMD -> 16 waves/CU (50%).
// BK=64 staging (proven r10 layout): A/B sub-block bi (16 rows x 32 k):
// wave w stages bi = w and bi = w+8 -> 4 gload16/thread/STAGE.
// ---------------------------------------------------------------------------

// ---------------------------------------------------------------------------
// Kernel 0: convert query [16.8M], W_in [262144], W_out [524288] fp32 -> fp16
// ---------------------------------------------------------------------------
__global__ __launch_bounds__(256) void k_cvt(const float* __restrict__ query,
                                             const float* __restrict__ Wi,
                                             const float* __restrict__ Wo,
                                             f16* __restrict__ q16,
                                             f16* __restrict__ W16)
{
    int i = blockIdx.x * 256 + threadIdx.x;   // float4 index, 4390912 total
    const float4* src;
    f16* dst;
    if (i < 4194304) { src = (const float4*)query + i; dst = q16 + (size_t)i * 4; }
    else if (i < 4259840) { int j = i - 4194304; src = (const float4*)Wi + j; dst = W16 + (size_t)j * 4; }
    else { int j = i - 4259840; src = (const float4*)Wo + j; dst = W16 + 262144 + (size_t)j * 4; }
    float4 v = *src;
    half4 h = {(f16)v.x, (f16)v.y, (f16)v.z, (f16)v.w};
    *reinterpret_cast<half4*>(dst) = h;
}

// ---------------------------------------------------------------------------
// Kernel 1: q = q16 @ W16^T. 128x128 tile, BK=64, 8 waves (512 thr).
// 1D grid 1024 with XCD swizzle. Counted-vmcnt pipeline.
// ---------------------------------------------------------------------------
__global__ __launch_bounds__(512, 4) void k_qin(const f16* __restrict__ q16,
                                                const f16* __restrict__ W16,
                                                f16* __restrict__ comb,
                                                f16* __restrict__ qT)
{
    __shared__ char sm[65536];
    const int tid = threadIdx.x, lane = tid & 63, w = tid >> 6;
    const int l15 = lane & 15, quad = lane >> 4;
    const int id = blockIdx.x, xcd = id & 7, u = id >> 3;
    const int mbase = (xcd * 32 + (u >> 2)) * 128;   // m-tile 0..255
    const int nbase = (u & 3) * 128;                 // n-tile 0..3
    const int wm = (w & 1) * 64, wn = (w >> 1) * 32;
    const int ia = (w & 1) * 4, jb = (w >> 1) * 2;

    floatx4 acc[4][2];
#pragma unroll
    for (int i = 0; i < 4; ++i)
#pragma unroll
        for (int j = 0; j < 2; ++j) acc[i][j] = (floatx4)0.f;

    auto STAGE = [&](int k0, int bsel) {   // 4 gload16 per thread
        f16* At = (f16*)(sm + bsel * 32768);
        f16* Bt = At + 8192;
#pragma unroll
        for (int jr = 0; jr < 2; ++jr) {
            int bi = jr * 8 + w, i2 = bi >> 1, s = bi & 1;
            gload16(q16 + (size_t)(mbase + i2 * 16 + l15) * 512 + k0 + s * 32 + quad * 8, At + bi * 512);
            gload16(W16 + (size_t)(nbase + i2 * 16 + l15) * 512 + k0 + s * 32 + quad * 8, Bt + bi * 512);
        }
    };

    STAGE(0, 0);
    STAGE(64, 1);
    for (int it = 0; it < 8; ++it) {
        const int cur = it & 1;
        if (it < 7) PHASE_WAIT_4(); else PHASE_WAIT_0();
        f16* At = (f16*)(sm + cur * 32768);
        f16* Bt = At + 8192;
#pragma unroll
        for (int s = 0; s < 2; ++s) {
            half8 a[4], bf[2];
#pragma unroll
            for (int i = 0; i < 4; ++i)
                a[i] = *reinterpret_cast<half8*>(At + ((ia + i) * 2 + s) * 512 + lane * 8);
#pragma unroll
            for (int j = 0; j < 2; ++j)
                bf[j] = *reinterpret_cast<half8*>(Bt + ((jb + j) * 2 + s) * 512 + lane * 8);
#pragma unroll
            for (int i = 0; i < 4; ++i)
#pragma unroll
                for (int j = 0; j < 2; ++j)
                    acc[i][j] = MFMA16(a[i], bf[j], acc[i][j]);
        }
        __builtin_amdgcn_s_barrier();   // all waves done reading cur
        if (it + 2 < 8) STAGE((it + 2) * 64, cur);
    }
    const int bb = mbase >> 11, tb = mbase & 2047;
    f16* ct = (f16*)sm;   // phase A: row-major [128][136] (aliases dead staging)
#pragma unroll
    for (int i = 0; i < 4; ++i)
#pragma unroll
        for (int j = 0; j < 2; ++j)
#pragma unroll
            for (int r = 0; r < 4; ++r)
                ct[(wm + i * 16 + quad * 4 + r) * 136 + wn + j * 16 + l15] = (f16)acc[i][j][r];
    __syncthreads();
#pragma unroll
    for (int it = 0; it < 4; ++it) {
        int c = it * 512 + tid, r = c >> 4, c8 = (c & 15) << 3;
        *reinterpret_cast<half8*>(comb + (size_t)(mbase + r) * 1024 + 512 + nbase + c8) =
            *reinterpret_cast<half8*>(ct + r * 136 + c8);
    }
    __syncthreads();
    // phase B: column-major [128 cols][136] — vectorized half4 dumps from acc
#pragma unroll
    for (int i = 0; i < 4; ++i)
#pragma unroll
        for (int j = 0; j < 2; ++j) {
            half4 h = {(f16)acc[i][j][0], (f16)acc[i][j][1], (f16)acc[i][j][2], (f16)acc[i][j][3]};
            *reinterpret_cast<half4*>(ct + (wn + j * 16 + l15) * 136 + wm + i * 16 + quad * 4) = h;
        }
    __syncthreads();
    // qT writes: 16 lanes share a d-row -> 256 B contiguous global segments
#pragma unroll
    for (int it = 0; it < 4; ++it) {
        int c = it * 512 + tid, dd = c >> 4, tc = (c & 15) << 3;
        *reinterpret_cast<half8*>(qT + ((size_t)bb * 512 + nbase + dd) * 2048 + tb + tc) =
            *reinterpret_cast<half8*>(ct + dd * 136 + tc);
    }
}

// ---------------------------------------------------------------------------
// Kernel 2: fused S-tile GEMM + PER-TILE softmax (parallel flash).
// One block per (b, causal tile), grid (16,136), 512 threads / 8 waves.
// BK=64 counted-vmcnt pipeline. Register epilogue: masked tile row max
// m_t, P_t = exp(S_t - m_t) fp16 (cached stores), row sums l_t.
// ---------------------------------------------------------------------------
__global__ __launch_bounds__(512, 4) void k_sgemmsm(const f16* __restrict__ comb,
                                                    f16* __restrict__ Pd,
                                                    float* __restrict__ Mt,
                                                    float* __restrict__ Lt)
{
    __shared__ char sm[65536];
    const int tid = threadIdx.x, lane = tid & 63, w = tid >> 6;
    const int l15 = lane & 15, quad = lane >> 4;
    const int wm = (w & 1) * 64, wn = (w >> 1) * 32;
    const int ia = (w & 1) * 4, jb = (w >> 1) * 2;

    int bx = blockIdx.y, mt = 0;
    while ((mt + 1) * (mt + 2) / 2 <= bx) ++mt;
    const int nt = bx - mt * (mt + 1) / 2;
    const int b = blockIdx.x;   // grid (16,136): id&7 = b&7 -> batch/XCD pin
    const f16* qa = comb + ((size_t)b * 2048 + mt * 128) * 1024 + 512;
    const f16* qb = comb + ((size_t)b * 2048 + nt * 128) * 1024 + 512;

    floatx4 acc[4][2];
#pragma unroll
    for (int i = 0; i < 4; ++i)
#pragma unroll
        for (int j = 0; j < 2; ++j) acc[i][j] = (floatx4)0.f;

    auto STAGE = [&](int k0, int bsel) {   // 4 gload16 per thread
        f16* At = (f16*)(sm + bsel * 32768);
        f16* Bt = At + 8192;
#pragma unroll
        for (int jr = 0; jr < 2; ++jr) {
            int bi = jr * 8 + w, i2 = bi >> 1, s = bi & 1;
            gload16(qa + (size_t)(i2 * 16 + l15) * 1024 + k0 + s * 32 + quad * 8, At + bi * 512);
            gload16(qb + (size_t)(i2 * 16 + l15) * 1024 + k0 + s * 32 + quad * 8, Bt + bi * 512);
        }
    };

    STAGE(0, 0);
    STAGE(64, 1);
    for (int it = 0; it < 8; ++it) {
        const int cur = it & 1;
        if (it < 7) PHASE_WAIT_4(); else PHASE_WAIT_0();
        f16* At = (f16*)(sm + cur * 32768);
        f16* Bt = At + 8192;
#pragma unroll
        for (int s = 0; s < 2; ++s) {
            half8 a[4], bf[2];
#pragma unroll
            for (int i = 0; i < 4; ++i)
                a[i] = *reinterpret_cast<half8*>(At + ((ia + i) * 2 + s) * 512 + lane * 8);
#pragma unroll
            for (int j = 0; j < 2; ++j)
                bf[j] = *reinterpret_cast<half8*>(Bt + ((jb + j) * 2 + s) * 512 + lane * 8);
#pragma unroll
            for (int i = 0; i < 4; ++i)
#pragma unroll
                for (int j = 0; j < 2; ++j)
                    acc[i][j] = MFMA16(a[i], bf[j], acc[i][j]);
        }
        __builtin_amdgcn_s_barrier();
        if (it + 2 < 8) STAGE((it + 2) * 64, cur);
    }

    // ---- per-tile softmax epilogue (8-wave layout) ----
    const bool diag = (nt == mt);
    f16* ct = (f16*)sm;                   // [128][136], aliases dead staging
    float* redm = (float*)(sm + 34816);   // [8 waves][64 rows] partial max
    float* reds = (float*)(sm + 36864);   // [8 waves][64 rows] partial sum
    const int hb = w & 1;

    // masked wave-partial row max (reduce over 2 j-regs + l15 lanes)
    float wmax[4][4];
#pragma unroll
    for (int i = 0; i < 4; ++i)
#pragma unroll
        for (int r = 0; r < 4; ++r) {
            const int rowl = wm + i * 16 + quad * 4 + r;
            float mm = -1e38f;
#pragma unroll
            for (int j = 0; j < 2; ++j) {
                float v = acc[i][j][r];
                if (diag && (wn + j * 16 + l15) >= rowl) v = -1e38f;
                mm = fmaxf(mm, v);
            }
            mm = fmaxf(mm, __shfl_xor(mm, 1));
            mm = fmaxf(mm, __shfl_xor(mm, 2));
            mm = fmaxf(mm, __shfl_xor(mm, 4));
            mm = fmaxf(mm, __shfl_xor(mm, 8));
            wmax[i][r] = mm;
        }
    if (l15 == 0)
#pragma unroll
        for (int i = 0; i < 4; ++i)
#pragma unroll
            for (int r = 0; r < 4; ++r)
                redm[w * 64 + i * 16 + quad * 4 + r] = wmax[i][r];
    __syncthreads();

    // exp + P->ct + row partial sums (combine max over 4 col-wave-groups)
#pragma unroll
    for (int i = 0; i < 4; ++i)
#pragma unroll
        for (int r = 0; r < 4; ++r) {
            const int idx = i * 16 + quad * 4 + r;
            const int rowl = wm + idx;
            const float m = fmaxf(fmaxf(redm[hb * 64 + idx], redm[(hb + 2) * 64 + idx]),
                                  fmaxf(redm[(hb + 4) * 64 + idx], redm[(hb + 6) * 64 + idx]));
            float ssum = 0.f;
#pragma unroll
            for (int j = 0; j < 2; ++j) {
                const int col = wn + j * 16 + l15;
                const bool valid = !diag || (col < rowl);
                float e = valid ? __expf(acc[i][j][r] - m) : 0.f;
                ssum += e;
                ct[rowl * 136 + col] = (f16)e;
            }
            ssum += __shfl_xor(ssum, 1);
            ssum += __shfl_xor(ssum, 2);
            ssum += __shfl_xor(ssum, 4);
            ssum += __shfl_xor(ssum, 8);
            wmax[i][r] = ssum;   // reuse as sum stash
        }
    if (l15 == 0)
#pragma unroll
        for (int i = 0; i < 4; ++i)
#pragma unroll
            for (int r = 0; r < 4; ++r)
                reds[w * 64 + i * 16 + quad * 4 + r] = wmax[i][r];
    __syncthreads();

    // m/l tables: one thread per row, contiguous 512B stores
    if (tid < 128) {
        const int h2 = tid >> 6, i2 = tid & 63;
        const float mm = fmaxf(fmaxf(redm[h2 * 64 + i2], redm[(h2 + 2) * 64 + i2]),
                               fmaxf(redm[(h2 + 4) * 64 + i2], redm[(h2 + 6) * 64 + i2]));
        const float ll = (reds[h2 * 64 + i2] + reds[(h2 + 2) * 64 + i2])
                       + (reds[(h2 + 4) * 64 + i2] + reds[(h2 + 6) * 64 + i2]);
        const size_t o = (((size_t)b * 16 + nt) << 11) + mt * 128 + tid;
        Mt[o] = mm;
        Lt[o] = ll;
    }
    // P' tile -> dense fp16 [b][tile][128][128], cached stores
    f16* Pt = Pd + ((size_t)(b * 136 + bx) << 14);
#pragma unroll
    for (int itp = 0; itp < 4; ++itp) {
        int c = itp * 512 + tid, r_ = c >> 4, c8 = (c & 15) << 3;
        *reinterpret_cast<half8*>(Pt + r_ * 128 + c8) =
            *reinterpret_cast<half8*>(ct + r_ * 136 + c8);
    }
}

// ---------------------------------------------------------------------------
// Kernel 3: combine per-tile stats -> per-tile scale factors, IN PLACE:
// F[b][t][row] = exp(m_t - M) / l  (0 if l==0, i.e. global row 0).
// ---------------------------------------------------------------------------
__global__ __launch_bounds__(256) void k_stats(float* Mt, const float* __restrict__ Lt)
{
    const int b = blockIdx.x, row = blockIdx.y * 256 + threadIdx.x;
    const int mtr = row >> 7;
    float mv[16], lv[16];
    for (int t = 0; t <= mtr; ++t) {
        const size_t o = (((size_t)b * 16 + t) << 11) + row;
        mv[t] = Mt[o];
        lv[t] = Lt[o];
    }
    float M = -1e38f;
    for (int t = 0; t <= mtr; ++t) M = fmaxf(M, mv[t]);
    float l = 0.f;
    for (int t = 0; t <= mtr; ++t) l += lv[t] * __expf(mv[t] - M);
    const float invl = (l > 0.f) ? 1.f / l : 0.f;
    for (int t = 0; t <= mtr; ++t)
        Mt[(((size_t)b * 16 + t) << 11) + row] = __expf(mv[t] - M) * invl;
}

// ---------------------------------------------------------------------------
// Kernel 3b: pre-scale P' rows by F -> P'' = final softmax weights.
// Grid (16,136) = same XCD pin as producer -> L2-hot.
// ---------------------------------------------------------------------------
__global__ __launch_bounds__(256) void k_pscale(f16* __restrict__ Pd,
                                               const float* __restrict__ Ft)
{
    int bx = blockIdx.y, mt = 0;
    while ((mt + 1) * (mt + 2) / 2 <= bx) ++mt;
    const int nt = bx - mt * (mt + 1) / 2;
    const int b = blockIdx.x;
    const int tid = threadIdx.x;
    const int row = tid >> 1, c0 = (tid & 1) * 64;   // 2 threads/row, 64 halves each
    const float Fv = Ft[(((size_t)b * 16 + nt) << 11) + mt * 128 + row];
    f16* Pt = Pd + ((size_t)(b * 136 + bx) << 14) + (size_t)row * 128 + c0;
#pragma unroll
    for (int c = 0; c < 8; ++c) {
        half8 h = *reinterpret_cast<half8*>(Pt + c * 8);
#pragma unroll
        for (int e = 0; e < 8; ++e) h[e] = (f16)((float)h[e] * Fv);
        *reinterpret_cast<half8*>(Pt + c * 8) = h;
    }
}

// ---------------------------------------------------------------------------
// Kernel 4: mix = P'' @ qT — pure GEMM. 128x128 tile, BK=64, 8 waves.
// Counted-vmcnt pipeline. Uniform-work pairing (mt=p with 15-p: 34
// K-iters/block, 512 blocks -> entire grid co-resident at 2 blocks/CU).
// ---------------------------------------------------------------------------
__global__ __launch_bounds__(512, 4) void k_pv(const f16* __restrict__ Pd,
                                               const f16* __restrict__ qT,
                                               f16* __restrict__ comb)
{
    __shared__ char sm[65536];
    const int tid = threadIdx.x, lane = tid & 63, w = tid >> 6;
    const int l15 = lane & 15, quad = lane >> 4;
    const int wm = (w & 1) * 64, wn = (w >> 1) * 32;
    const int ia = (w & 1) * 4, jb = (w >> 1) * 2;
    const int id = blockIdx.x;
    const int p = id & 7, nb = (id >> 3) & 3, b = id >> 5;
    const f16* Pdb = Pd + ((size_t)b * 136 << 14);
    const f16* qTb = qT + ((size_t)b * 512 + nb * 128) * 2048;

    for (int t = 0; t < 2; ++t) {
        const int mt = t ? (15 - p) : p;
        const int tb0 = mt * (mt + 1) / 2;
        const int kit = (mt + 1) * 2;

        floatx4 acc[4][2];
#pragma unroll
        for (int i = 0; i < 4; ++i)
#pragma unroll
            for (int j = 0; j < 2; ++j) acc[i][j] = (floatx4)0.f;

        auto STAGE = [&](int it, int bsel) {   // 4 gload16 per thread
            f16* At = (f16*)(sm + bsel * 32768);
            f16* Bt = At + 8192;
            const int k0 = it * 64;
#pragma unroll
            for (int jr = 0; jr < 2; ++jr) {
                int bi = jr * 8 + w, i2 = bi >> 1, s = bi & 1;
                gload16(Pdb + ((size_t)(tb0 + (k0 >> 7)) << 14) + (size_t)(i2 * 16 + l15) * 128
                            + (k0 & 64) + s * 32 + quad * 8,
                        At + bi * 512);
                gload16(qTb + (size_t)(i2 * 16 + l15) * 2048 + k0 + s * 32 + quad * 8, Bt + bi * 512);
            }
        };

        STAGE(0, 0);
        STAGE(1, 1);
        for (int it = 0; it < kit; ++it) {
            const int cur = it & 1;
            if (it < kit - 1) PHASE_WAIT_4(); else PHASE_WAIT_0();
            f16* At = (f16*)(sm + cur * 32768);
            f16* Bt = At + 8192;
#pragma unroll
            for (int s = 0; s < 2; ++s) {
                half8 a[4], bf[2];
#pragma unroll
                for (int i = 0; i < 4; ++i)
                    a[i] = *reinterpret_cast<half8*>(At + ((ia + i) * 2 + s) * 512 + lane * 8);
#pragma unroll
                for (int j = 0; j < 2; ++j)
                    bf[j] = *reinterpret_cast<half8*>(Bt + ((jb + j) * 2 + s) * 512 + lane * 8);
#pragma unroll
                for (int i = 0; i < 4; ++i)
#pragma unroll
                    for (int j = 0; j < 2; ++j)
                        acc[i][j] = MFMA16(a[i], bf[j], acc[i][j]);
            }
            __builtin_amdgcn_s_barrier();   // all waves done reading cur
            if (it + 2 < kit) STAGE(it + 2, cur);
        }

        // epilogue: bounce via ct (aliases dead staging bufs), store comb
        f16* ct = (f16*)sm;
#pragma unroll
        for (int i = 0; i < 4; ++i)
#pragma unroll
            for (int j = 0; j < 2; ++j)
#pragma unroll
                for (int r = 0; r < 4; ++r)
                    ct[(wm + i * 16 + quad * 4 + r) * 136 + wn + j * 16 + l15] = (f16)acc[i][j][r];
        __syncthreads();
#pragma unroll
        for (int it = 0; it < 4; ++it) {
            int c = it * 512 + tid, r = c >> 4, c8 = (c & 15) << 3;
            *reinterpret_cast<half8*>(comb + ((size_t)b * 2048 + mt * 128 + r) * 1024 + nb * 128 + c8) =
                *reinterpret_cast<half8*>(ct + r * 136 + c8);
        }
        __syncthreads();   // ct reads done before next tile re-stages over it
    }
}

// ---------------------------------------------------------------------------
// Kernel 5: out = comb @ W_out^T (fp32 out). K=1024, BK=64, 8 waves.
// 1D grid 1024, XCD swizzle, counted-vmcnt pipeline. NT full-line stores.
// ---------------------------------------------------------------------------
__global__ __launch_bounds__(512, 4) void k_out(const f16* __restrict__ comb,
                                                const f16* __restrict__ Wo16,
                                                float* __restrict__ out)
{
    __shared__ char sm[65536];
    const int tid = threadIdx.x, lane = tid & 63, w = tid >> 6;
    const int l15 = lane & 15, quad = lane >> 4;
    const int id = blockIdx.x, xcd = id & 7, u = id >> 3;
    const int mbase = (xcd * 32 + (u >> 2)) * 128;
    const int nbase = (u & 3) * 128;
    const int wn = (w >> 1) * 32;
    const int ia = (w & 1) * 4, jb = (w >> 1) * 2;

    floatx4 acc[4][2];
#pragma unroll
    for (int i = 0; i < 4; ++i)
#pragma unroll
        for (int j = 0; j < 2; ++j) acc[i][j] = (floatx4)0.f;

    auto STAGE = [&](int k0, int bsel) {   // 4 gload16 per thread
        f16* At = (f16*)(sm + bsel * 32768);
        f16* Bt = At + 8192;
#pragma unroll
        for (int jr = 0; jr < 2; ++jr) {
            int bi = jr * 8 + w, i2 = bi >> 1, s = bi & 1;
            gload16(comb + (size_t)(mbase + i2 * 16 + l15) * 1024 + k0 + s * 32 + quad * 8,
                    At + bi * 512);
            gload16(Wo16 + (size_t)(nbase + i2 * 16 + l15) * 1024 + k0 + s * 32 + quad * 8,
                    Bt + bi * 512);
        }
    };

    STAGE(0, 0);
    STAGE(64, 1);
    for (int it = 0; it < 16; ++it) {
        const int cur = it & 1;
        if (it < 15) PHASE_WAIT_4(); else PHASE_WAIT_0();
        f16* At = (f16*)(sm + cur * 32768);
        f16* Bt = At + 8192;
#pragma unroll
        for (int s = 0; s < 2; ++s) {
            half8 a[4], bf[2];
#pragma unroll
            for (int i = 0; i < 4; ++i)
                a[i] = *reinterpret_cast<half8*>(At + ((ia + i) * 2 + s) * 512 + lane * 8);
#pragma unroll
            for (int j = 0; j < 2; ++j)
                bf[j] = *reinterpret_cast<half8*>(Bt + ((jb + j) * 2 + s) * 512 + lane * 8);
#pragma unroll
            for (int i = 0; i < 4; ++i)
#pragma unroll
                for (int j = 0; j < 2; ++j)
                    acc[i][j] = MFMA16(a[i], bf[j], acc[i][j]);
        }
        __builtin_amdgcn_s_barrier();
        if (it + 2 < 16) STAGE((it + 2) * 64, cur);
    }
    float* cf = (float*)sm;   // [64][132] fp32 padded
    for (int pass = 0; pass < 2; ++pass) {
        __syncthreads();
        if ((w & 1) == pass) {   // 4 waves own rows pass*64..+63
#pragma unroll
            for (int i = 0; i < 4; ++i)
#pragma unroll
                for (int j = 0; j < 2; ++j)
#pragma unroll
                    for (int r = 0; r < 4; ++r)
                        cf[(i * 16 + quad * 4 + r) * 132 + wn + j * 16 + l15] = acc[i][j][r];
        }
        __syncthreads();
#pragma unroll
        for (int it = 0; it < 4; ++it) {
            int c = it * 512 + tid, row = c >> 5, c4 = (c & 31) << 2;
            __builtin_nontemporal_store(
                *reinterpret_cast<floatx4*>(cf + row * 132 + c4),
                reinterpret_cast<floatx4*>(out + (size_t)(mbase + pass * 64 + row) * 512 + nbase + c4));
        }
    }
}

extern "C" void kernel_launch(void* const* d_in, const int* in_sizes, int n_in,
                              void* d_out, int out_size, void* d_ws, size_t ws_size,
                              hipStream_t stream)
{
    const float* query = (const float*)d_in[0];
    const float* W_in  = (const float*)d_in[1];
    const float* W_out = (const float*)d_in[2];
    float* out = (float*)d_out;

    // ws layout (bytes):
    //   comb fp16 [32768][1024] (mix|q)        @ 0           (67,108,864)
    //   qT   fp16 [16][512][2048]              @ 67,108,864  (33,554,432)
    //   W16  fp16 [Wi 262144 | Wo 524288]      @ 100,663,296 (1,572,864)
    //   X    @ 102,236,160:
    //     q16 fp16 [16*2048*512] (33,554,432)  -- dead after k_qin
    //     Pd  fp16 [16][136][128][128]         @ XOFF        (71,303,168) aliases q16
    //     Mt  f32  [16][16][2048] (m_t -> F_t) @ +71,303,168 (2,097,152)
    //     Lt  f32  [16][16][2048] (l_t)        @ +73,400,320 (2,097,152)
    const size_t XOFF = 102236160ull;
    f16* comb = (f16*)d_ws;
    f16* qT   = comb + (size_t)32768 * 1024;
    f16* W16  = qT + (size_t)16 * 512 * 2048;
    f16* q16  = (f16*)((char*)d_ws + XOFF);
    f16* Pd   = (f16*)((char*)d_ws + XOFF);
    float* Mt = (float*)((char*)d_ws + XOFF + 71303168ull);
    float* Lt = (float*)((char*)d_ws + XOFF + 73400320ull);

    k_cvt<<<17152, 256, 0, stream>>>(query, W_in, W_out, q16, W16);
    k_qin<<<1024, 512, 0, stream>>>(q16, W16, comb, qT);
    k_sgemmsm<<<dim3(16, 136), 512, 0, stream>>>(comb, Pd, Mt, Lt);
    k_stats<<<dim3(16, 8), 256, 0, stream>>>(Mt, Lt);
    k_pscale<<<dim3(16, 136), 256, 0, stream>>>(Pd, Mt);
    k_pv<<<512, 512, 0, stream>>>(Pd, qT, comb);
    k_out<<<1024, 512, 0, stream>>>(comb, W16 + 262144, out);
}

// Round 14
// 373.550 us; speedup vs baseline: 1.0933x; 1.0933x over previous
//
#include <hip/hip_runtime.h>

typedef _Float16 f16;
typedef _Float16 half8 __attribute__((ext_vector_type(8)));
typedef _Float16 half4 __attribute__((ext_vector_type(4)));
typedef float floatx4 __attribute__((ext_vector_type(4)));

#define MFMA16(a, b, c) __builtin_amdgcn_mfma_f32_16x16x32_f16(a, b, c, 0, 0, 0)

// counted-vmcnt phase gate: wait until only the NEXT tile's 4 staging loads
// remain in flight (FIFO: current tile's 4 are older -> retired first),
// fence the scheduler, then raw barrier (no implicit drain).
#define PHASE_WAIT_4()  do { asm volatile("s_waitcnt vmcnt(4)" ::: "memory"); \
    __builtin_amdgcn_sched_barrier(0); __builtin_amdgcn_s_barrier(); } while (0)
#define PHASE_WAIT_0()  do { asm volatile("s_waitcnt vmcnt(0)" ::: "memory"); \
    __builtin_amdgcn_sched_barrier(0); __builtin_amdgcn_s_barrier(); } while (0)

// async global->LDS, 16B per lane; LDS side = wave-uniform base + lane*16
__device__ __forceinline__ void gload16(const void* g, void* l) {
    __builtin_amdgcn_global_load_lds((const __attribute__((address_space(1))) void*)g,
                                     (__attribute__((address_space(3))) void*)l, 16, 0, 0);
}

// ---------------------------------------------------------------------------
// v9 theory: every GEMM variant (r4/r10/r12/r13) pinned at ~92 us with no
// pipe >31% -> bound by L2-miss traffic served by Infinity Cache at ~6.7TB/s
// (k_sgemmsm: 557MB logical q re-reads; per-XCD working set was 2 batches
// = 4MB = exactly L2, thrashed by the P' write stream). Fix = locality:
// (1) k_sgemmsm: one batch per XCD at a time (grid 8x272, second batch
//     half dispatches after the first drains) -> 2MB q fits L2.
// (2) k_pv: pin by BATCH (id&7=b&7), nb/p blocks of one batch share the
//     XCD -> P'/qT strips L2-hit. F folded in via LDS table (k_pscale
//     deleted; LDS reads don't perturb the counted-vmcnt FIFO).
// ---------------------------------------------------------------------------

// ---------------------------------------------------------------------------
// Kernel 0: convert query [16.8M], W_in [262144], W_out [524288] fp32 -> fp16
// ---------------------------------------------------------------------------
__global__ __launch_bounds__(256) void k_cvt(const float* __restrict__ query,
                                             const float* __restrict__ Wi,
                                             const float* __restrict__ Wo,
                                             f16* __restrict__ q16,
                                             f16* __restrict__ W16)
{
    int i = blockIdx.x * 256 + threadIdx.x;   // float4 index, 4390912 total
    const float4* src;
    f16* dst;
    if (i < 4194304) { src = (const float4*)query + i; dst = q16 + (size_t)i * 4; }
    else if (i < 4259840) { int j = i - 4194304; src = (const float4*)Wi + j; dst = W16 + (size_t)j * 4; }
    else { int j = i - 4259840; src = (const float4*)Wo + j; dst = W16 + 262144 + (size_t)j * 4; }
    float4 v = *src;
    half4 h = {(f16)v.x, (f16)v.y, (f16)v.z, (f16)v.w};
    *reinterpret_cast<half4*>(dst) = h;
}

// ---------------------------------------------------------------------------
// Kernel 1: q = q16 @ W16^T. 128x128 tile, BK=64, 8 waves (512 thr).
// 1D grid 1024 with XCD swizzle. Counted-vmcnt pipeline.
// ---------------------------------------------------------------------------
__global__ __launch_bounds__(512, 4) void k_qin(const f16* __restrict__ q16,
                                                const f16* __restrict__ W16,
                                                f16* __restrict__ comb,
                                                f16* __restrict__ qT)
{
    __shared__ char sm[65536];
    const int tid = threadIdx.x, lane = tid & 63, w = tid >> 6;
    const int l15 = lane & 15, quad = lane >> 4;
    const int id = blockIdx.x, xcd = id & 7, u = id >> 3;
    const int mbase = (xcd * 32 + (u >> 2)) * 128;   // m-tile 0..255
    const int nbase = (u & 3) * 128;                 // n-tile 0..3
    const int wm = (w & 1) * 64, wn = (w >> 1) * 32;
    const int ia = (w & 1) * 4, jb = (w >> 1) * 2;

    floatx4 acc[4][2];
#pragma unroll
    for (int i = 0; i < 4; ++i)
#pragma unroll
        for (int j = 0; j < 2; ++j) acc[i][j] = (floatx4)0.f;

    auto STAGE = [&](int k0, int bsel) {   // 4 gload16 per thread
        f16* At = (f16*)(sm + bsel * 32768);
        f16* Bt = At + 8192;
#pragma unroll
        for (int jr = 0; jr < 2; ++jr) {
            int bi = jr * 8 + w, i2 = bi >> 1, s = bi & 1;
            gload16(q16 + (size_t)(mbase + i2 * 16 + l15) * 512 + k0 + s * 32 + quad * 8, At + bi * 512);
            gload16(W16 + (size_t)(nbase + i2 * 16 + l15) * 512 + k0 + s * 32 + quad * 8, Bt + bi * 512);
        }
    };

    STAGE(0, 0);
    STAGE(64, 1);
    for (int it = 0; it < 8; ++it) {
        const int cur = it & 1;
        if (it < 7) PHASE_WAIT_4(); else PHASE_WAIT_0();
        f16* At = (f16*)(sm + cur * 32768);
        f16* Bt = At + 8192;
#pragma unroll
        for (int s = 0; s < 2; ++s) {
            half8 a[4], bf[2];
#pragma unroll
            for (int i = 0; i < 4; ++i)
                a[i] = *reinterpret_cast<half8*>(At + ((ia + i) * 2 + s) * 512 + lane * 8);
#pragma unroll
            for (int j = 0; j < 2; ++j)
                bf[j] = *reinterpret_cast<half8*>(Bt + ((jb + j) * 2 + s) * 512 + lane * 8);
#pragma unroll
            for (int i = 0; i < 4; ++i)
#pragma unroll
                for (int j = 0; j < 2; ++j)
                    acc[i][j] = MFMA16(a[i], bf[j], acc[i][j]);
        }
        __builtin_amdgcn_s_barrier();   // all waves done reading cur
        if (it + 2 < 8) STAGE((it + 2) * 64, cur);
    }
    const int bb = mbase >> 11, tb = mbase & 2047;
    f16* ct = (f16*)sm;   // phase A: row-major [128][136] (aliases dead staging)
#pragma unroll
    for (int i = 0; i < 4; ++i)
#pragma unroll
        for (int j = 0; j < 2; ++j)
#pragma unroll
            for (int r = 0; r < 4; ++r)
                ct[(wm + i * 16 + quad * 4 + r) * 136 + wn + j * 16 + l15] = (f16)acc[i][j][r];
    __syncthreads();
#pragma unroll
    for (int it = 0; it < 4; ++it) {
        int c = it * 512 + tid, r = c >> 4, c8 = (c & 15) << 3;
        *reinterpret_cast<half8*>(comb + (size_t)(mbase + r) * 1024 + 512 + nbase + c8) =
            *reinterpret_cast<half8*>(ct + r * 136 + c8);
    }
    __syncthreads();
    // phase B: column-major [128 cols][136] — vectorized half4 dumps from acc
#pragma unroll
    for (int i = 0; i < 4; ++i)
#pragma unroll
        for (int j = 0; j < 2; ++j) {
            half4 h = {(f16)acc[i][j][0], (f16)acc[i][j][1], (f16)acc[i][j][2], (f16)acc[i][j][3]};
            *reinterpret_cast<half4*>(ct + (wn + j * 16 + l15) * 136 + wm + i * 16 + quad * 4) = h;
        }
    __syncthreads();
    // qT writes: 16 lanes share a d-row -> 256 B contiguous global segments
#pragma unroll
    for (int it = 0; it < 4; ++it) {
        int c = it * 512 + tid, dd = c >> 4, tc = (c & 15) << 3;
        *reinterpret_cast<half8*>(qT + ((size_t)bb * 512 + nbase + dd) * 2048 + tb + tc) =
            *reinterpret_cast<half8*>(ct + dd * 136 + tc);
    }
}

// ---------------------------------------------------------------------------
// Kernel 2: fused S-tile GEMM + PER-TILE softmax (parallel flash).
// v9: grid (8, 272) — XCD x runs ALL 136 tiles of batch x, then batch x+8
// (second half dispatches after first drains) -> concurrent q working set
// per XCD = 2 MB, fits the 4 MB L2 -> strip re-reads (17x amplification)
// become L2 hits instead of Infinity-Cache traffic.
// 512 threads / 8 waves, BK=64 counted-vmcnt pipeline.
// ---------------------------------------------------------------------------
__global__ __launch_bounds__(512, 4) void k_sgemmsm(const f16* __restrict__ comb,
                                                    f16* __restrict__ Pd,
                                                    float* __restrict__ Mt,
                                                    float* __restrict__ Lt)
{
    __shared__ char sm[65536];
    const int tid = threadIdx.x, lane = tid & 63, w = tid >> 6;
    const int l15 = lane & 15, quad = lane >> 4;
    const int wm = (w & 1) * 64, wn = (w >> 1) * 32;
    const int ia = (w & 1) * 4, jb = (w >> 1) * 2;

    const int bhalf = (blockIdx.y >= 136) ? 1 : 0;
    int bx = blockIdx.y - bhalf * 136, mt = 0;
    while ((mt + 1) * (mt + 2) / 2 <= bx) ++mt;
    const int nt = bx - mt * (mt + 1) / 2;
    const int b = blockIdx.x + bhalf * 8;   // id&7 = blockIdx.x = b&7 -> XCD pin
    const f16* qa = comb + ((size_t)b * 2048 + mt * 128) * 1024 + 512;
    const f16* qb = comb + ((size_t)b * 2048 + nt * 128) * 1024 + 512;

    floatx4 acc[4][2];
#pragma unroll
    for (int i = 0; i < 4; ++i)
#pragma unroll
        for (int j = 0; j < 2; ++j) acc[i][j] = (floatx4)0.f;

    auto STAGE = [&](int k0, int bsel) {   // 4 gload16 per thread
        f16* At = (f16*)(sm + bsel * 32768);
        f16* Bt = At + 8192;
#pragma unroll
        for (int jr = 0; jr < 2; ++jr) {
            int bi = jr * 8 + w, i2 = bi >> 1, s = bi & 1;
            gload16(qa + (size_t)(i2 * 16 + l15) * 1024 + k0 + s * 32 + quad * 8, At + bi * 512);
            gload16(qb + (size_t)(i2 * 16 + l15) * 1024 + k0 + s * 32 + quad * 8, Bt + bi * 512);
        }
    };

    STAGE(0, 0);
    STAGE(64, 1);
    for (int it = 0; it < 8; ++it) {
        const int cur = it & 1;
        if (it < 7) PHASE_WAIT_4(); else PHASE_WAIT_0();
        f16* At = (f16*)(sm + cur * 32768);
        f16* Bt = At + 8192;
#pragma unroll
        for (int s = 0; s < 2; ++s) {
            half8 a[4], bf[2];
#pragma unroll
            for (int i = 0; i < 4; ++i)
                a[i] = *reinterpret_cast<half8*>(At + ((ia + i) * 2 + s) * 512 + lane * 8);
#pragma unroll
            for (int j = 0; j < 2; ++j)
                bf[j] = *reinterpret_cast<half8*>(Bt + ((jb + j) * 2 + s) * 512 + lane * 8);
#pragma unroll
            for (int i = 0; i < 4; ++i)
#pragma unroll
                for (int j = 0; j < 2; ++j)
                    acc[i][j] = MFMA16(a[i], bf[j], acc[i][j]);
        }
        __builtin_amdgcn_s_barrier();
        if (it + 2 < 8) STAGE((it + 2) * 64, cur);
    }

    // ---- per-tile softmax epilogue (8-wave layout) ----
    const bool diag = (nt == mt);
    f16* ct = (f16*)sm;                   // [128][136], aliases dead staging
    float* redm = (float*)(sm + 34816);   // [8 waves][64 rows] partial max
    float* reds = (float*)(sm + 36864);   // [8 waves][64 rows] partial sum
    const int hb = w & 1;

    // masked wave-partial row max (reduce over 2 j-regs + l15 lanes)
    float wmax[4][4];
#pragma unroll
    for (int i = 0; i < 4; ++i)
#pragma unroll
        for (int r = 0; r < 4; ++r) {
            const int rowl = wm + i * 16 + quad * 4 + r;
            float mm = -1e38f;
#pragma unroll
            for (int j = 0; j < 2; ++j) {
                float v = acc[i][j][r];
                if (diag && (wn + j * 16 + l15) >= rowl) v = -1e38f;
                mm = fmaxf(mm, v);
            }
            mm = fmaxf(mm, __shfl_xor(mm, 1));
            mm = fmaxf(mm, __shfl_xor(mm, 2));
            mm = fmaxf(mm, __shfl_xor(mm, 4));
            mm = fmaxf(mm, __shfl_xor(mm, 8));
            wmax[i][r] = mm;
        }
    if (l15 == 0)
#pragma unroll
        for (int i = 0; i < 4; ++i)
#pragma unroll
            for (int r = 0; r < 4; ++r)
                redm[w * 64 + i * 16 + quad * 4 + r] = wmax[i][r];
    __syncthreads();

    // exp + P->ct + row partial sums (combine max over 4 col-wave-groups)
#pragma unroll
    for (int i = 0; i < 4; ++i)
#pragma unroll
        for (int r = 0; r < 4; ++r) {
            const int idx = i * 16 + quad * 4 + r;
            const int rowl = wm + idx;
            const float m = fmaxf(fmaxf(redm[hb * 64 + idx], redm[(hb + 2) * 64 + idx]),
                                  fmaxf(redm[(hb + 4) * 64 + idx], redm[(hb + 6) * 64 + idx]));
            float ssum = 0.f;
#pragma unroll
            for (int j = 0; j < 2; ++j) {
                const int col = wn + j * 16 + l15;
                const bool valid = !diag || (col < rowl);
                float e = valid ? __expf(acc[i][j][r] - m) : 0.f;
                ssum += e;
                ct[rowl * 136 + col] = (f16)e;
            }
            ssum += __shfl_xor(ssum, 1);
            ssum += __shfl_xor(ssum, 2);
            ssum += __shfl_xor(ssum, 4);
            ssum += __shfl_xor(ssum, 8);
            wmax[i][r] = ssum;   // reuse as sum stash
        }
    if (l15 == 0)
#pragma unroll
        for (int i = 0; i < 4; ++i)
#pragma unroll
            for (int r = 0; r < 4; ++r)
                reds[w * 64 + i * 16 + quad * 4 + r] = wmax[i][r];
    __syncthreads();

    // m/l tables: one thread per row, contiguous 512B stores
    if (tid < 128) {
        const int h2 = tid >> 6, i2 = tid & 63;
        const float mm = fmaxf(fmaxf(redm[h2 * 64 + i2], redm[(h2 + 2) * 64 + i2]),
                               fmaxf(redm[(h2 + 4) * 64 + i2], redm[(h2 + 6) * 64 + i2]));
        const float ll = (reds[h2 * 64 + i2] + reds[(h2 + 2) * 64 + i2])
                       + (reds[(h2 + 4) * 64 + i2] + reds[(h2 + 6) * 64 + i2]);
        const size_t o = (((size_t)b * 16 + nt) << 11) + mt * 128 + tid;
        Mt[o] = mm;
        Lt[o] = ll;
    }
    // P' tile -> dense fp16 [b][tile][128][128], cached stores
    f16* Pt = Pd + ((size_t)(b * 136 + bx) << 14);
#pragma unroll
    for (int itp = 0; itp < 4; ++itp) {
        int c = itp * 512 + tid, r_ = c >> 4, c8 = (c & 15) << 3;
        *reinterpret_cast<half8*>(Pt + r_ * 128 + c8) =
            *reinterpret_cast<half8*>(ct + r_ * 136 + c8);
    }
}

// ---------------------------------------------------------------------------
// Kernel 3: combine per-tile stats -> per-tile scale factors, IN PLACE:
// F[b][t][row] = exp(m_t - M) / l  (0 if l==0, i.e. global row 0).
// ---------------------------------------------------------------------------
__global__ __launch_bounds__(256) void k_stats(float* Mt, const float* __restrict__ Lt)
{
    const int b = blockIdx.x, row = blockIdx.y * 256 + threadIdx.x;
    const int mtr = row >> 7;
    float mv[16], lv[16];
    for (int t = 0; t <= mtr; ++t) {
        const size_t o = (((size_t)b * 16 + t) << 11) + row;
        mv[t] = Mt[o];
        lv[t] = Lt[o];
    }
    float M = -1e38f;
    for (int t = 0; t <= mtr; ++t) M = fmaxf(M, mv[t]);
    float l = 0.f;
    for (int t = 0; t <= mtr; ++t) l += lv[t] * __expf(mv[t] - M);
    const float invl = (l > 0.f) ? 1.f / l : 0.f;
    for (int t = 0; t <= mtr; ++t)
        Mt[(((size_t)b * 16 + t) << 11) + row] = __expf(mv[t] - M) * invl;
}

// ---------------------------------------------------------------------------
// Kernel 4: mix = sum_t F_t * (P_t @ qT_t). v9:
//  - BATCH pin: id = xcd + 8*(nb + 4*(p + 8*half)), b = xcd + 8*half ->
//    id&7 = b&7; the 4 nb-blocks and 8 p-blocks of one batch share the
//    XCD -> P' strips and qT strips L2-hit (was: pin by p -> all 16
//    batches per XCD -> 170MB HBM fetch).
//  - F-table in LDS (8 KiB @ +64K, dynamic 72 KiB total): staged per
//    tile-pass before the prologue (then __syncthreads drains vmcnt=0 so
//    counted-wait bookkeeping holds); per-tile fold reads LDS (lgkmcnt)
//    -> never perturbs the vmcnt FIFO. k_pscale deleted (~142MB saved).
//  - acc (per-tile) + accT (weighted total): VGPR ~52+32, well under 128.
// ---------------------------------------------------------------------------
__global__ __launch_bounds__(512, 4) void k_pv(const f16* __restrict__ Pd,
                                               const f16* __restrict__ qT,
                                               f16* __restrict__ comb,
                                               const float* __restrict__ Ft)
{
    extern __shared__ char sm[];   // 73728: [0,64K) staging dbuf, [64K,+8K) F
    const int tid = threadIdx.x, lane = tid & 63, w = tid >> 6;
    const int l15 = lane & 15, quad = lane >> 4;
    const int wm = (w & 1) * 64, wn = (w >> 1) * 32;
    const int ia = (w & 1) * 4, jb = (w >> 1) * 2;
    const int id = blockIdx.x;
    const int xcd = id & 7, v = id >> 3;
    const int nb = v & 3, p = (v >> 2) & 7, half_ = v >> 5;
    const int b = xcd + 8 * half_;
    const f16* Pdb = Pd + ((size_t)b * 136 << 14);
    const f16* qTb = qT + ((size_t)b * 512 + nb * 128) * 2048;
    float* F_lds = (float*)(sm + 65536);

    for (int t = 0; t < 2; ++t) {
        const int mt = t ? (15 - p) : p;
        const int tb0 = mt * (mt + 1) / 2;
        const int kit = (mt + 1) * 2;

        // stage F[b][tt][mt*128 + row] for tt=0..mt -> F_lds[tt*128+row]
        if (tid * 4 < (mt + 1) * 128) {
            const int idx = tid * 4, tt = idx >> 7, r4 = idx & 127;
            *reinterpret_cast<floatx4*>(F_lds + idx) =
                *reinterpret_cast<const floatx4*>(Ft + (((size_t)b * 16 + tt) << 11) + mt * 128 + r4);
        }
        __syncthreads();   // F visible to all; drains vmcnt -> prologue count clean

        floatx4 acc[4][2], accT[4][2];
#pragma unroll
        for (int i = 0; i < 4; ++i)
#pragma unroll
            for (int j = 0; j < 2; ++j) { acc[i][j] = (floatx4)0.f; accT[i][j] = (floatx4)0.f; }

        auto STAGE = [&](int it, int bsel) {   // 4 gload16 per thread
            f16* At = (f16*)(sm + bsel * 32768);
            f16* Bt = At + 8192;
            const int k0 = it * 64;
#pragma unroll
            for (int jr = 0; jr < 2; ++jr) {
                int bi = jr * 8 + w, i2 = bi >> 1, s = bi & 1;
                gload16(Pdb + ((size_t)(tb0 + (k0 >> 7)) << 14) + (size_t)(i2 * 16 + l15) * 128
                            + (k0 & 64) + s * 32 + quad * 8,
                        At + bi * 512);
                gload16(qTb + (size_t)(i2 * 16 + l15) * 2048 + k0 + s * 32 + quad * 8, Bt + bi * 512);
            }
        };

        STAGE(0, 0);
        STAGE(1, 1);
        for (int it = 0; it < kit; ++it) {
            const int cur = it & 1;
            if (it < kit - 1) PHASE_WAIT_4(); else PHASE_WAIT_0();
            f16* At = (f16*)(sm + cur * 32768);
            f16* Bt = At + 8192;
#pragma unroll
            for (int s = 0; s < 2; ++s) {
                half8 a[4], bf[2];
#pragma unroll
                for (int i = 0; i < 4; ++i)
                    a[i] = *reinterpret_cast<half8*>(At + ((ia + i) * 2 + s) * 512 + lane * 8);
#pragma unroll
                for (int j = 0; j < 2; ++j)
                    bf[j] = *reinterpret_cast<half8*>(Bt + ((jb + j) * 2 + s) * 512 + lane * 8);
#pragma unroll
                for (int i = 0; i < 4; ++i)
#pragma unroll
                    for (int j = 0; j < 2; ++j)
                        acc[i][j] = MFMA16(a[i], bf[j], acc[i][j]);
            }
            if (it & 1) {   // tile (it>>1) complete: fold with F from LDS, reset
                const int tt = it >> 1;
                const float* fp = F_lds + tt * 128 + wm;
#pragma unroll
                for (int i = 0; i < 4; ++i) {
                    floatx4 fv = *reinterpret_cast<const floatx4*>(fp + i * 16 + quad * 4);
#pragma unroll
                    for (int j = 0; j < 2; ++j) {
                        accT[i][j] += acc[i][j] * fv;
                        acc[i][j] = (floatx4)0.f;
                    }
                }
            }
            __builtin_amdgcn_s_barrier();   // all waves done reading cur
            if (it + 2 < kit) STAGE(it + 2, cur);
        }

        // epilogue: bounce via ct (aliases dead staging bufs), store comb
        f16* ct = (f16*)sm;
#pragma unroll
        for (int i = 0; i < 4; ++i)
#pragma unroll
            for (int j = 0; j < 2; ++j)
#pragma unroll
                for (int r = 0; r < 4; ++r)
                    ct[(wm + i * 16 + quad * 4 + r) * 136 + wn + j * 16 + l15] = (f16)accT[i][j][r];
        __syncthreads();
#pragma unroll
        for (int it = 0; it < 4; ++it) {
            int c = it * 512 + tid, r = c >> 4, c8 = (c & 15) << 3;
            *reinterpret_cast<half8*>(comb + ((size_t)b * 2048 + mt * 128 + r) * 1024 + nb * 128 + c8) =
                *reinterpret_cast<half8*>(ct + r * 136 + c8);
        }
        __syncthreads();   // ct reads done before next tile re-stages over it
    }
}

// ---------------------------------------------------------------------------
// Kernel 5: out = comb @ W_out^T (fp32 out). K=1024, BK=64, 8 waves.
// 1D grid 1024, XCD swizzle, counted-vmcnt pipeline. NT full-line stores.
// ---------------------------------------------------------------------------
__global__ __launch_bounds__(512, 4) void k_out(const f16* __restrict__ comb,
                                                const f16* __restrict__ Wo16,
                                                float* __restrict__ out)
{
    __shared__ char sm[65536];
    const int tid = threadIdx.x, lane = tid & 63, w = tid >> 6;
    const int l15 = lane & 15, quad = lane >> 4;
    const int id = blockIdx.x, xcd = id & 7, u = id >> 3;
    const int mbase = (xcd * 32 + (u >> 2)) * 128;
    const int nbase = (u & 3) * 128;
    const int wn = (w >> 1) * 32;
    const int ia = (w & 1) * 4, jb = (w >> 1) * 2;

    floatx4 acc[4][2];
#pragma unroll
    for (int i = 0; i < 4; ++i)
#pragma unroll
        for (int j = 0; j < 2; ++j) acc[i][j] = (floatx4)0.f;

    auto STAGE = [&](int k0, int bsel) {   // 4 gload16 per thread
        f16* At = (f16*)(sm + bsel * 32768);
        f16* Bt = At + 8192;
#pragma unroll
        for (int jr = 0; jr < 2; ++jr) {
            int bi = jr * 8 + w, i2 = bi >> 1, s = bi & 1;
            gload16(comb + (size_t)(mbase + i2 * 16 + l15) * 1024 + k0 + s * 32 + quad * 8,
                    At + bi * 512);
            gload16(Wo16 + (size_t)(nbase + i2 * 16 + l15) * 1024 + k0 + s * 32 + quad * 8,
                    Bt + bi * 512);
        }
    };

    STAGE(0, 0);
    STAGE(64, 1);
    for (int it = 0; it < 16; ++it) {
        const int cur = it & 1;
        if (it < 15) PHASE_WAIT_4(); else PHASE_WAIT_0();
        f16* At = (f16*)(sm + cur * 32768);
        f16* Bt = At + 8192;
#pragma unroll
        for (int s = 0; s < 2; ++s) {
            half8 a[4], bf[2];
#pragma unroll
            for (int i = 0; i < 4; ++i)
                a[i] = *reinterpret_cast<half8*>(At + ((ia + i) * 2 + s) * 512 + lane * 8);
#pragma unroll
            for (int j = 0; j < 2; ++j)
                bf[j] = *reinterpret_cast<half8*>(Bt + ((jb + j) * 2 + s) * 512 + lane * 8);
#pragma unroll
            for (int i = 0; i < 4; ++i)
#pragma unroll
                for (int j = 0; j < 2; ++j)
                    acc[i][j] = MFMA16(a[i], bf[j], acc[i][j]);
        }
        __builtin_amdgcn_s_barrier();
        if (it + 2 < 16) STAGE((it + 2) * 64, cur);
    }
    float* cf = (float*)sm;   // [64][132] fp32 padded
    for (int pass = 0; pass < 2; ++pass) {
        __syncthreads();
        if ((w & 1) == pass) {   // 4 waves own rows pass*64..+63
#pragma unroll
            for (int i = 0; i < 4; ++i)
#pragma unroll
                for (int j = 0; j < 2; ++j)
#pragma unroll
                    for (int r = 0; r < 4; ++r)
                        cf[(i * 16 + quad * 4 + r) * 132 + wn + j * 16 + l15] = acc[i][j][r];
        }
        __syncthreads();
#pragma unroll
        for (int it = 0; it < 4; ++it) {
            int c = it * 512 + tid, row = c >> 5, c4 = (c & 31) << 2;
            __builtin_nontemporal_store(
                *reinterpret_cast<floatx4*>(cf + row * 132 + c4),
                reinterpret_cast<floatx4*>(out + (size_t)(mbase + pass * 64 + row) * 512 + nbase + c4));
        }
    }
}

extern "C" void kernel_launch(void* const* d_in, const int* in_sizes, int n_in,
                              void* d_out, int out_size, void* d_ws, size_t ws_size,
                              hipStream_t stream)
{
    const float* query = (const float*)d_in[0];
    const float* W_in  = (const float*)d_in[1];
    const float* W_out = (const float*)d_in[2];
    float* out = (float*)d_out;

    // ws layout (bytes):
    //   comb fp16 [32768][1024] (mix|q)        @ 0           (67,108,864)
    //   qT   fp16 [16][512][2048]              @ 67,108,864  (33,554,432)
    //   W16  fp16 [Wi 262144 | Wo 524288]      @ 100,663,296 (1,572,864)
    //   X    @ 102,236,160:
    //     q16 fp16 [16*2048*512] (33,554,432)  -- dead after k_qin
    //     Pd  fp16 [16][136][128][128]         @ XOFF        (71,303,168) aliases q16
    //     Mt  f32  [16][16][2048] (m_t -> F_t) @ +71,303,168 (2,097,152)
    //     Lt  f32  [16][16][2048] (l_t)        @ +73,400,320 (2,097,152)
    const size_t XOFF = 102236160ull;
    f16* comb = (f16*)d_ws;
    f16* qT   = comb + (size_t)32768 * 1024;
    f16* W16  = qT + (size_t)16 * 512 * 2048;
    f16* q16  = (f16*)((char*)d_ws + XOFF);
    f16* Pd   = (f16*)((char*)d_ws + XOFF);
    float* Mt = (float*)((char*)d_ws + XOFF + 71303168ull);
    float* Lt = (float*)((char*)d_ws + XOFF + 73400320ull);

    k_cvt<<<17152, 256, 0, stream>>>(query, W_in, W_out, q16, W16);
    k_qin<<<1024, 512, 0, stream>>>(q16, W16, comb, qT);
    k_sgemmsm<<<dim3(8, 272), 512, 0, stream>>>(comb, Pd, Mt, Lt);
    k_stats<<<dim3(16, 8), 256, 0, stream>>>(Mt, Lt);
    k_pv<<<512, 512, 73728, stream>>>(Pd, qT, comb, Mt);
    k_out<<<1024, 512, 0, stream>>>(comb, W16 + 262144, out);
}

// Round 15
// 372.325 us; speedup vs baseline: 1.0969x; 1.0033x over previous
//
#include <hip/hip_runtime.h>

typedef _Float16 f16;
typedef _Float16 half8 __attribute__((ext_vector_type(8)));
typedef _Float16 half4 __attribute__((ext_vector_type(4)));
typedef float floatx4 __attribute__((ext_vector_type(4)));

#define MFMA16(a, b, c) __builtin_amdgcn_mfma_f32_16x16x32_f16(a, b, c, 0, 0, 0)

// counted-vmcnt phase gates (N = loads/STAGE still in flight for next buffer)
#define PHASE_WAIT_4()  do { asm volatile("s_waitcnt vmcnt(4)" ::: "memory"); \
    __builtin_amdgcn_sched_barrier(0); __builtin_amdgcn_s_barrier(); } while (0)
#define PHASE_WAIT_8()  do { asm volatile("s_waitcnt vmcnt(8)" ::: "memory"); \
    __builtin_amdgcn_sched_barrier(0); __builtin_amdgcn_s_barrier(); } while (0)
#define PHASE_WAIT_0()  do { asm volatile("s_waitcnt vmcnt(0)" ::: "memory"); \
    __builtin_amdgcn_sched_barrier(0); __builtin_amdgcn_s_barrier(); } while (0)

// async global->LDS, 16B per lane; LDS side = wave-uniform base + lane*16
__device__ __forceinline__ void gload16(const void* g, void* l) {
    __builtin_amdgcn_global_load_lds((const __attribute__((address_space(1))) void*)g,
                                     (__attribute__((address_space(3))) void*)l, 16, 0, 0);
}

// ---------------------------------------------------------------------------
// v10 theory: six k_sgemmsm variants all pinned at 92-94us = 388 TF = 15.5%
// MfmaUtil with FETCH ranging 141->17MB -> not traffic, not occupancy: the
// 128^2 tile gives only 16 MFMA per barrier pair (m233's 2-phase stall).
// 256^2 macro-tiles quadruple MFMA:barrier (64/pair); guide m230/m248
// measured 655-682 TF at this config. k_sgemmsm + k_out converted;
// k_qin/k_pv keep the r14 structure (rewrite-risk budget).
// ---------------------------------------------------------------------------

// ---------------------------------------------------------------------------
// Kernel 0: convert query [16.8M], W_in [262144], W_out [524288] fp32 -> fp16
// ---------------------------------------------------------------------------
__global__ __launch_bounds__(256) void k_cvt(const float* __restrict__ query,
                                             const float* __restrict__ Wi,
                                             const float* __restrict__ Wo,
                                             f16* __restrict__ q16,
                                             f16* __restrict__ W16)
{
    int i = blockIdx.x * 256 + threadIdx.x;   // float4 index, 4390912 total
    const float4* src;
    f16* dst;
    if (i < 4194304) { src = (const float4*)query + i; dst = q16 + (size_t)i * 4; }
    else if (i < 4259840) { int j = i - 4194304; src = (const float4*)Wi + j; dst = W16 + (size_t)j * 4; }
    else { int j = i - 4259840; src = (const float4*)Wo + j; dst = W16 + 262144 + (size_t)j * 4; }
    float4 v = *src;
    half4 h = {(f16)v.x, (f16)v.y, (f16)v.z, (f16)v.w};
    *reinterpret_cast<half4*>(dst) = h;
}

// ---------------------------------------------------------------------------
// Kernel 1: q = q16 @ W16^T. 128x128 tile, BK=64, 8 waves (512 thr).
// 1D grid 1024 with XCD swizzle. Counted-vmcnt pipeline. (unchanged r14)
// ---------------------------------------------------------------------------
__global__ __launch_bounds__(512, 4) void k_qin(const f16* __restrict__ q16,
                                                const f16* __restrict__ W16,
                                                f16* __restrict__ comb,
                                                f16* __restrict__ qT)
{
    __shared__ char sm[65536];
    const int tid = threadIdx.x, lane = tid & 63, w = tid >> 6;
    const int l15 = lane & 15, quad = lane >> 4;
    const int id = blockIdx.x, xcd = id & 7, u = id >> 3;
    const int mbase = (xcd * 32 + (u >> 2)) * 128;   // m-tile 0..255
    const int nbase = (u & 3) * 128;                 // n-tile 0..3
    const int wm = (w & 1) * 64, wn = (w >> 1) * 32;
    const int ia = (w & 1) * 4, jb = (w >> 1) * 2;

    floatx4 acc[4][2];
#pragma unroll
    for (int i = 0; i < 4; ++i)
#pragma unroll
        for (int j = 0; j < 2; ++j) acc[i][j] = (floatx4)0.f;

    auto STAGE = [&](int k0, int bsel) {   // 4 gload16 per thread
        f16* At = (f16*)(sm + bsel * 32768);
        f16* Bt = At + 8192;
#pragma unroll
        for (int jr = 0; jr < 2; ++jr) {
            int bi = jr * 8 + w, i2 = bi >> 1, s = bi & 1;
            gload16(q16 + (size_t)(mbase + i2 * 16 + l15) * 512 + k0 + s * 32 + quad * 8, At + bi * 512);
            gload16(W16 + (size_t)(nbase + i2 * 16 + l15) * 512 + k0 + s * 32 + quad * 8, Bt + bi * 512);
        }
    };

    STAGE(0, 0);
    STAGE(64, 1);
    for (int it = 0; it < 8; ++it) {
        const int cur = it & 1;
        if (it < 7) PHASE_WAIT_4(); else PHASE_WAIT_0();
        f16* At = (f16*)(sm + cur * 32768);
        f16* Bt = At + 8192;
#pragma unroll
        for (int s = 0; s < 2; ++s) {
            half8 a[4], bf[2];
#pragma unroll
            for (int i = 0; i < 4; ++i)
                a[i] = *reinterpret_cast<half8*>(At + ((ia + i) * 2 + s) * 512 + lane * 8);
#pragma unroll
            for (int j = 0; j < 2; ++j)
                bf[j] = *reinterpret_cast<half8*>(Bt + ((jb + j) * 2 + s) * 512 + lane * 8);
#pragma unroll
            for (int i = 0; i < 4; ++i)
#pragma unroll
                for (int j = 0; j < 2; ++j)
                    acc[i][j] = MFMA16(a[i], bf[j], acc[i][j]);
        }
        __builtin_amdgcn_s_barrier();   // all waves done reading cur
        if (it + 2 < 8) STAGE((it + 2) * 64, cur);
    }
    const int bb = mbase >> 11, tb = mbase & 2047;
    f16* ct = (f16*)sm;   // phase A: row-major [128][136] (aliases dead staging)
#pragma unroll
    for (int i = 0; i < 4; ++i)
#pragma unroll
        for (int j = 0; j < 2; ++j)
#pragma unroll
            for (int r = 0; r < 4; ++r)
                ct[(wm + i * 16 + quad * 4 + r) * 136 + wn + j * 16 + l15] = (f16)acc[i][j][r];
    __syncthreads();
#pragma unroll
    for (int it = 0; it < 4; ++it) {
        int c = it * 512 + tid, r = c >> 4, c8 = (c & 15) << 3;
        *reinterpret_cast<half8*>(comb + (size_t)(mbase + r) * 1024 + 512 + nbase + c8) =
            *reinterpret_cast<half8*>(ct + r * 136 + c8);
    }
    __syncthreads();
    // phase B: column-major [128 cols][136] — vectorized half4 dumps from acc
#pragma unroll
    for (int i = 0; i < 4; ++i)
#pragma unroll
        for (int j = 0; j < 2; ++j) {
            half4 h = {(f16)acc[i][j][0], (f16)acc[i][j][1], (f16)acc[i][j][2], (f16)acc[i][j][3]};
            *reinterpret_cast<half4*>(ct + (wn + j * 16 + l15) * 136 + wm + i * 16 + quad * 4) = h;
        }
    __syncthreads();
    // qT writes: 16 lanes share a d-row -> 256 B contiguous global segments
#pragma unroll
    for (int it = 0; it < 4; ++it) {
        int c = it * 512 + tid, dd = c >> 4, tc = (c & 15) << 3;
        *reinterpret_cast<half8*>(qT + ((size_t)bb * 512 + nbase + dd) * 2048 + tb + tc) =
            *reinterpret_cast<half8*>(ct + dd * 136 + tc);
    }
}

// ---------------------------------------------------------------------------
// Kernel 2: fused S GEMM + per-tile softmax, v10: 256x256 MACRO-TILES.
// grid (8, 72): xcd = blockIdx.x, macro u = y%36 (triangular 8x8), batch
// b = xcd + 8*(y>=36) (sequential halves keep q L2-resident per XCD).
// 8 waves: wave w -> row-half rh=w&1 (128 rows), col-quarter cq=w>>1 (64
// cols); acc[8][4]. BK=64 dbuf (128 KiB) counted-vmcnt: 64 MFMA/barrier
// pair (4x the 128^2 ratio). Epilogue: per-128^2-quadrant softmax stats
// (same Mt/Lt/Pd formats); diag macro masks at element level; the
// all-masked quadrant (rh=0,ch=1) is never stored (k_pv reads nt<=mt only).
// Dynamic LDS 143360: [0,128K) staging / ct[256][260]; redm/reds above.
// ---------------------------------------------------------------------------
__global__ __launch_bounds__(512, 2) void k_sgemmsm(const f16* __restrict__ comb,
                                                    f16* __restrict__ Pd,
                                                    float* __restrict__ Mt,
                                                    float* __restrict__ Lt)
{
    extern __shared__ char sm[];
    const int tid = threadIdx.x, lane = tid & 63, w = tid >> 6;
    const int l15 = lane & 15, quad = lane >> 4;
    const int rh = w & 1, cq = w >> 1;

    const int bhalf = (blockIdx.y >= 36) ? 1 : 0;
    int u = blockIdx.y - bhalf * 36, mM = 0;
    while ((mM + 1) * (mM + 2) / 2 <= u) ++mM;
    const int nM = u - mM * (mM + 1) / 2;
    const int b = blockIdx.x + bhalf * 8;
    const bool diagM = (nM == mM);
    const f16* qa = comb + ((size_t)b * 2048 + mM * 256) * 1024 + 512;
    const f16* qb = comb + ((size_t)b * 2048 + nM * 256) * 1024 + 512;

    floatx4 acc[8][4];
#pragma unroll
    for (int i = 0; i < 8; ++i)
#pragma unroll
        for (int j = 0; j < 4; ++j) acc[i][j] = (floatx4)0.f;

    auto STAGE = [&](int k0, int bsel) {   // 8 gload16 per thread
        f16* At = (f16*)sm + bsel * 32768;   // 32768 halfs = 64 KiB buffer
        f16* Bt = At + 16384;
#pragma unroll
        for (int jr = 0; jr < 4; ++jr) {
            int bi = jr * 8 + w, i2 = bi >> 1, s = bi & 1;
            gload16(qa + (size_t)(i2 * 16 + l15) * 1024 + k0 + s * 32 + quad * 8, At + bi * 512);
            gload16(qb + (size_t)(i2 * 16 + l15) * 1024 + k0 + s * 32 + quad * 8, Bt + bi * 512);
        }
    };

    STAGE(0, 0);
    STAGE(64, 1);
    for (int it = 0; it < 8; ++it) {
        const int cur = it & 1;
        if (it < 7) PHASE_WAIT_8(); else PHASE_WAIT_0();
        f16* At = (f16*)sm + cur * 32768;
        f16* Bt = At + 16384;
#pragma unroll
        for (int s = 0; s < 2; ++s) {
            half8 a[8], bf[4];
#pragma unroll
            for (int i = 0; i < 8; ++i)
                a[i] = *reinterpret_cast<half8*>(At + ((rh * 8 + i) * 2 + s) * 512 + lane * 8);
#pragma unroll
            for (int j = 0; j < 4; ++j)
                bf[j] = *reinterpret_cast<half8*>(Bt + ((cq * 4 + j) * 2 + s) * 512 + lane * 8);
#pragma unroll
            for (int i = 0; i < 8; ++i)
#pragma unroll
                for (int j = 0; j < 4; ++j)
                    acc[i][j] = MFMA16(a[i], bf[j], acc[i][j]);
        }
        __builtin_amdgcn_s_barrier();   // all waves done reading cur
        if (it + 2 < 8) STAGE((it + 2) * 64, cur);
    }

    // ---- per-quadrant softmax epilogue ----
    float* redm = (float*)(sm + 135168);   // [8 waves][128 rows] partial max
    float* reds = (float*)(sm + 139264);   // [8 waves][128 rows] partial sum
    const int gr0 = mM * 256 + rh * 128;   // wave's global row base
    const int gc0 = nM * 256 + cq * 64;    // wave's global col base
    const int ch = cq >> 1;                // wave's col-half (128-tile)

    float st[8][4];
    // masked wave-partial row max over this wave's 64 cols
#pragma unroll
    for (int i = 0; i < 8; ++i)
#pragma unroll
        for (int r = 0; r < 4; ++r) {
            const int rowl = i * 16 + quad * 4 + r;
            const int gr = gr0 + rowl;
            float mm = -1e38f;
#pragma unroll
            for (int j = 0; j < 4; ++j) {
                float v = acc[i][j][r];
                if (diagM && (gc0 + j * 16 + l15) >= gr) v = -1e38f;
                mm = fmaxf(mm, v);
            }
            mm = fmaxf(mm, __shfl_xor(mm, 1));
            mm = fmaxf(mm, __shfl_xor(mm, 2));
            mm = fmaxf(mm, __shfl_xor(mm, 4));
            mm = fmaxf(mm, __shfl_xor(mm, 8));
            st[i][r] = mm;
        }
    if (l15 == 0)
#pragma unroll
        for (int i = 0; i < 8; ++i)
#pragma unroll
            for (int r = 0; r < 4; ++r)
                redm[w * 128 + i * 16 + quad * 4 + r] = st[i][r];
    __syncthreads();

    // exp (per col-half max) + row partial sums; acc overwritten with e
#pragma unroll
    for (int i = 0; i < 8; ++i)
#pragma unroll
        for (int r = 0; r < 4; ++r) {
            const int rowl = i * 16 + quad * 4 + r;
            const int gr = gr0 + rowl;
            const float m = fmaxf(redm[(rh + 4 * ch) * 128 + rowl],
                                  redm[(rh + 4 * ch + 2) * 128 + rowl]);
            float ssum = 0.f;
#pragma unroll
            for (int j = 0; j < 4; ++j) {
                const bool valid = !diagM || ((gc0 + j * 16 + l15) < gr);
                float e = valid ? __expf(acc[i][j][r] - m) : 0.f;
                ssum += e;
                acc[i][j][r] = e;
            }
            ssum += __shfl_xor(ssum, 1);
            ssum += __shfl_xor(ssum, 2);
            ssum += __shfl_xor(ssum, 4);
            ssum += __shfl_xor(ssum, 8);
            st[i][r] = ssum;
        }
    if (l15 == 0)
#pragma unroll
        for (int i = 0; i < 8; ++i)
#pragma unroll
            for (int r = 0; r < 4; ++r)
                reds[w * 128 + i * 16 + quad * 4 + r] = st[i][r];
    __syncthreads();

    // Mt/Lt: one thread per (quadrant, row); skip invalid quadrants
    {
        const int row = tid & 127, sub = tid >> 7;
        const int rh2 = sub & 1, ch2 = sub >> 1;
        const int mtt = 2 * mM + rh2, nt = 2 * nM + ch2;
        if (nt <= mtt) {
            const float mm = fmaxf(redm[(rh2 + 4 * ch2) * 128 + row],
                                   redm[(rh2 + 4 * ch2 + 2) * 128 + row]);
            const float ll = reds[(rh2 + 4 * ch2) * 128 + row]
                           + reds[(rh2 + 4 * ch2 + 2) * 128 + row];
            const size_t o = (((size_t)b * 16 + nt) << 11) + mtt * 128 + row;
            Mt[o] = mm;
            Lt[o] = ll;
        }
    }

    // P' -> ct [256][260] (aliases dead staging; redm/reds live above 132K)
    f16* ct = (f16*)sm;
#pragma unroll
    for (int i = 0; i < 8; ++i)
#pragma unroll
        for (int j = 0; j < 4; ++j)
#pragma unroll
            for (int r = 0; r < 4; ++r)
                ct[(rh * 128 + i * 16 + quad * 4 + r) * 260 + cq * 64 + j * 16 + l15] =
                    (f16)acc[i][j][r];
    __syncthreads();
    // store valid quadrants to Pd (cached: re-read by k_pv)
#pragma unroll
    for (int sub = 0; sub < 4; ++sub) {
        const int rh2 = sub & 1, ch2 = sub >> 1;
        const int mtt = 2 * mM + rh2, nt = 2 * nM + ch2;
        if (nt > mtt) continue;
        f16* Pt = Pd + ((size_t)(b * 136 + mtt * (mtt + 1) / 2 + nt) << 14);
#pragma unroll
        for (int itp = 0; itp < 4; ++itp) {
            int c = itp * 512 + tid, rr = c >> 4, c8 = (c & 15) << 3;
            *reinterpret_cast<half8*>(Pt + rr * 128 + c8) =
                *reinterpret_cast<half8*>(ct + (rh2 * 128 + rr) * 260 + ch2 * 128 + c8);
        }
    }
}

// ---------------------------------------------------------------------------
// Kernel 3: combine per-tile stats -> per-tile scale factors, IN PLACE:
// F[b][t][row] = exp(m_t - M) / l  (0 if l==0, i.e. global row 0).
// ---------------------------------------------------------------------------
__global__ __launch_bounds__(256) void k_stats(float* Mt, const float* __restrict__ Lt)
{
    const int b = blockIdx.x, row = blockIdx.y * 256 + threadIdx.x;
    const int mtr = row >> 7;
    float mv[16], lv[16];
    for (int t = 0; t <= mtr; ++t) {
        const size_t o = (((size_t)b * 16 + t) << 11) + row;
        mv[t] = Mt[o];
        lv[t] = Lt[o];
    }
    float M = -1e38f;
    for (int t = 0; t <= mtr; ++t) M = fmaxf(M, mv[t]);
    float l = 0.f;
    for (int t = 0; t <= mtr; ++t) l += lv[t] * __expf(mv[t] - M);
    const float invl = (l > 0.f) ? 1.f / l : 0.f;
    for (int t = 0; t <= mtr; ++t)
        Mt[(((size_t)b * 16 + t) << 11) + row] = __expf(mv[t] - M) * invl;
}

// ---------------------------------------------------------------------------
// Kernel 4: mix = sum_t F_t * (P_t @ qT_t). Batch-pinned, F-table in LDS,
// counted-vmcnt, uniform pairing. (unchanged r14 — left top-5 last round)
// ---------------------------------------------------------------------------
__global__ __launch_bounds__(512, 4) void k_pv(const f16* __restrict__ Pd,
                                               const f16* __restrict__ qT,
                                               f16* __restrict__ comb,
                                               const float* __restrict__ Ft)
{
    extern __shared__ char sm[];   // 73728: [0,64K) staging dbuf, [64K,+8K) F
    const int tid = threadIdx.x, lane = tid & 63, w = tid >> 6;
    const int l15 = lane & 15, quad = lane >> 4;
    const int wm = (w & 1) * 64, wn = (w >> 1) * 32;
    const int ia = (w & 1) * 4, jb = (w >> 1) * 2;
    const int id = blockIdx.x;
    const int xcd = id & 7, v = id >> 3;
    const int nb = v & 3, p = (v >> 2) & 7, half_ = v >> 5;
    const int b = xcd + 8 * half_;
    const f16* Pdb = Pd + ((size_t)b * 136 << 14);
    const f16* qTb = qT + ((size_t)b * 512 + nb * 128) * 2048;
    float* F_lds = (float*)(sm + 65536);

    for (int t = 0; t < 2; ++t) {
        const int mt = t ? (15 - p) : p;
        const int tb0 = mt * (mt + 1) / 2;
        const int kit = (mt + 1) * 2;

        // stage F[b][tt][mt*128 + row] for tt=0..mt -> F_lds[tt*128+row]
        if (tid * 4 < (mt + 1) * 128) {
            const int idx = tid * 4, tt = idx >> 7, r4 = idx & 127;
            *reinterpret_cast<floatx4*>(F_lds + idx) =
                *reinterpret_cast<const floatx4*>(Ft + (((size_t)b * 16 + tt) << 11) + mt * 128 + r4);
        }
        __syncthreads();   // F visible; drains vmcnt -> prologue count clean

        floatx4 acc[4][2], accT[4][2];
#pragma unroll
        for (int i = 0; i < 4; ++i)
#pragma unroll
            for (int j = 0; j < 2; ++j) { acc[i][j] = (floatx4)0.f; accT[i][j] = (floatx4)0.f; }

        auto STAGE = [&](int it, int bsel) {   // 4 gload16 per thread
            f16* At = (f16*)(sm + bsel * 32768);
            f16* Bt = At + 8192;
            const int k0 = it * 64;
#pragma unroll
            for (int jr = 0; jr < 2; ++jr) {
                int bi = jr * 8 + w, i2 = bi >> 1, s = bi & 1;
                gload16(Pdb + ((size_t)(tb0 + (k0 >> 7)) << 14) + (size_t)(i2 * 16 + l15) * 128
                            + (k0 & 64) + s * 32 + quad * 8,
                        At + bi * 512);
                gload16(qTb + (size_t)(i2 * 16 + l15) * 2048 + k0 + s * 32 + quad * 8, Bt + bi * 512);
            }
        };

        STAGE(0, 0);
        STAGE(1, 1);
        for (int it = 0; it < kit; ++it) {
            const int cur = it & 1;
            if (it < kit - 1) PHASE_WAIT_4(); else PHASE_WAIT_0();
            f16* At = (f16*)(sm + cur * 32768);
            f16* Bt = At + 8192;
#pragma unroll
            for (int s = 0; s < 2; ++s) {
                half8 a[4], bf[2];
#pragma unroll
                for (int i = 0; i < 4; ++i)
                    a[i] = *reinterpret_cast<half8*>(At + ((ia + i) * 2 + s) * 512 + lane * 8);
#pragma unroll
                for (int j = 0; j < 2; ++j)
                    bf[j] = *reinterpret_cast<half8*>(Bt + ((jb + j) * 2 + s) * 512 + lane * 8);
#pragma unroll
                for (int i = 0; i < 4; ++i)
#pragma unroll
                    for (int j = 0; j < 2; ++j)
                        acc[i][j] = MFMA16(a[i], bf[j], acc[i][j]);
            }
            if (it & 1) {   // tile (it>>1) complete: fold with F from LDS, reset
                const int tt = it >> 1;
                const float* fp = F_lds + tt * 128 + wm;
#pragma unroll
                for (int i = 0; i < 4; ++i) {
                    floatx4 fv = *reinterpret_cast<const floatx4*>(fp + i * 16 + quad * 4);
#pragma unroll
                    for (int j = 0; j < 2; ++j) {
                        accT[i][j] += acc[i][j] * fv;
                        acc[i][j] = (floatx4)0.f;
                    }
                }
            }
            __builtin_amdgcn_s_barrier();   // all waves done reading cur
            if (it + 2 < kit) STAGE(it + 2, cur);
        }

        // epilogue: bounce via ct (aliases dead staging bufs), store comb
        f16* ct = (f16*)sm;
#pragma unroll
        for (int i = 0; i < 4; ++i)
#pragma unroll
            for (int j = 0; j < 2; ++j)
#pragma unroll
                for (int r = 0; r < 4; ++r)
                    ct[(wm + i * 16 + quad * 4 + r) * 136 + wn + j * 16 + l15] = (f16)accT[i][j][r];
        __syncthreads();
#pragma unroll
        for (int it = 0; it < 4; ++it) {
            int c = it * 512 + tid, r = c >> 4, c8 = (c & 15) << 3;
            *reinterpret_cast<half8*>(comb + ((size_t)b * 2048 + mt * 128 + r) * 1024 + nb * 128 + c8) =
                *reinterpret_cast<half8*>(ct + r * 136 + c8);
        }
        __syncthreads();   // ct reads done before next tile re-stages over it
    }
}

// ---------------------------------------------------------------------------
// Kernel 5: out = comb @ W_out^T (fp32 out). v10: 256x256 macro-tiles,
// 256 blocks = exactly one co-resident generation. K=1024, BK=64 dbuf
// (128 KiB) counted-vmcnt, 64 MFMA/barrier pair. Two-pass fp32 LDS bounce
// (cf [128][268] aliases dead staging) + NT full-line stores.
// Dynamic LDS 139264.
// ---------------------------------------------------------------------------
__global__ __launch_bounds__(512, 2) void k_out(const f16* __restrict__ comb,
                                                const f16* __restrict__ Wo16,
                                                float* __restrict__ out)
{
    extern __shared__ char sm[];
    const int tid = threadIdx.x, lane = tid & 63, w = tid >> 6;
    const int l15 = lane & 15, quad = lane >> 4;
    const int rh = w & 1, cq = w >> 1;
    const int id = blockIdx.x, xcd = id & 7, u = id >> 3;   // u in [0,32)
    const int mbase = (xcd * 16 + (u >> 1)) * 256;
    const int nbase = (u & 1) * 256;

    floatx4 acc[8][4];
#pragma unroll
    for (int i = 0; i < 8; ++i)
#pragma unroll
        for (int j = 0; j < 4; ++j) acc[i][j] = (floatx4)0.f;

    auto STAGE = [&](int k0, int bsel) {   // 8 gload16 per thread
        f16* At = (f16*)sm + bsel * 32768;
        f16* Bt = At + 16384;
#pragma unroll
        for (int jr = 0; jr < 4; ++jr) {
            int bi = jr * 8 + w, i2 = bi >> 1, s = bi & 1;
            gload16(comb + (size_t)(mbase + i2 * 16 + l15) * 1024 + k0 + s * 32 + quad * 8,
                    At + bi * 512);
            gload16(Wo16 + (size_t)(nbase + i2 * 16 + l15) * 1024 + k0 + s * 32 + quad * 8,
                    Bt + bi * 512);
        }
    };

    STAGE(0, 0);
    STAGE(64, 1);
    for (int it = 0; it < 16; ++it) {
        const int cur = it & 1;
        if (it < 15) PHASE_WAIT_8(); else PHASE_WAIT_0();
        f16* At = (f16*)sm + cur * 32768;
        f16* Bt = At + 16384;
#pragma unroll
        for (int s = 0; s < 2; ++s) {
            half8 a[8], bf[4];
#pragma unroll
            for (int i = 0; i < 8; ++i)
                a[i] = *reinterpret_cast<half8*>(At + ((rh * 8 + i) * 2 + s) * 512 + lane * 8);
#pragma unroll
            for (int j = 0; j < 4; ++j)
                bf[j] = *reinterpret_cast<half8*>(Bt + ((cq * 4 + j) * 2 + s) * 512 + lane * 8);
#pragma unroll
            for (int i = 0; i < 8; ++i)
#pragma unroll
                for (int j = 0; j < 4; ++j)
                    acc[i][j] = MFMA16(a[i], bf[j], acc[i][j]);
        }
        __builtin_amdgcn_s_barrier();
        if (it + 2 < 16) STAGE((it + 2) * 64, cur);
    }
    float* cf = (float*)sm;   // [128][268] fp32, aliases dead staging
    for (int pass = 0; pass < 2; ++pass) {
        __syncthreads();
        if (rh == pass) {
#pragma unroll
            for (int i = 0; i < 8; ++i)
#pragma unroll
                for (int j = 0; j < 4; ++j)
#pragma unroll
                    for (int r = 0; r < 4; ++r)
                        cf[(i * 16 + quad * 4 + r) * 268 + cq * 64 + j * 16 + l15] = acc[i][j][r];
        }
        __syncthreads();
#pragma unroll
        for (int it = 0; it < 16; ++it) {
            int c = it * 512 + tid, row = c >> 6, c4 = (c & 63) << 2;
            __builtin_nontemporal_store(
                *reinterpret_cast<floatx4*>(cf + row * 268 + c4),
                reinterpret_cast<floatx4*>(out + (size_t)(mbase + pass * 128 + row) * 512 + nbase + c4));
        }
    }
}

extern "C" void kernel_launch(void* const* d_in, const int* in_sizes, int n_in,
                              void* d_out, int out_size, void* d_ws, size_t ws_size,
                              hipStream_t stream)
{
    const float* query = (const float*)d_in[0];
    const float* W_in  = (const float*)d_in[1];
    const float* W_out = (const float*)d_in[2];
    float* out = (float*)d_out;

    // ws layout (bytes):
    //   comb fp16 [32768][1024] (mix|q)        @ 0           (67,108,864)
    //   qT   fp16 [16][512][2048]              @ 67,108,864  (33,554,432)
    //   W16  fp16 [Wi 262144 | Wo 524288]      @ 100,663,296 (1,572,864)
    //   X    @ 102,236,160:
    //     q16 fp16 [16*2048*512] (33,554,432)  -- dead after k_qin
    //     Pd  fp16 [16][136][128][128]         @ XOFF        (71,303,168) aliases q16
    //     Mt  f32  [16][16][2048] (m_t -> F_t) @ +71,303,168 (2,097,152)
    //     Lt  f32  [16][16][2048] (l_t)        @ +73,400,320 (2,097,152)
    const size_t XOFF = 102236160ull;
    f16* comb = (f16*)d_ws;
    f16* qT   = comb + (size_t)32768 * 1024;
    f16* W16  = qT + (size_t)16 * 512 * 2048;
    f16* q16  = (f16*)((char*)d_ws + XOFF);
    f16* Pd   = (f16*)((char*)d_ws + XOFF);
    float* Mt = (float*)((char*)d_ws + XOFF + 71303168ull);
    float* Lt = (float*)((char*)d_ws + XOFF + 73400320ull);

    k_cvt<<<17152, 256, 0, stream>>>(query, W_in, W_out, q16, W16);
    k_qin<<<1024, 512, 0, stream>>>(q16, W16, comb, qT);
    k_sgemmsm<<<dim3(8, 72), 512, 143360, stream>>>(comb, Pd, Mt, Lt);
    k_stats<<<dim3(16, 8), 256, 0, stream>>>(Mt, Lt);
    k_pv<<<512, 512, 73728, stream>>>(Pd, qT, comb, Mt);
    k_out<<<256, 512, 139264, stream>>>(comb, W16 + 262144, out);
}